// Round 1
// baseline (776.153 us; speedup 1.0000x reference)
//
#include <hip/hip_runtime.h>

#define NN 100000
#define NE 600000
#define DD 128
#define SCAN_CHUNK 2048
#define NCHUNK 49  /* ceil(NN / SCAN_CHUNK) */

__device__ __forceinline__ float frelu(float x) { return x > 0.f ? x : 0.f; }

// ---- edge_index dtype detector: int64 (little-endian) => odd words all zero ----
__global__ void k_detect(const int* __restrict__ ei, int* __restrict__ flag)
{
    if (blockIdx.x == 0 && threadIdx.x == 0) {
        int z = 1;
        for (int i = 0; i < 64; ++i)
            if (ei[2 * i + 1] != 0) { z = 0; break; }
        flag[0] = z;
    }
}

__global__ void k_count(const int* __restrict__ ei, const int* __restrict__ flag,
                        int* __restrict__ deg)
{
    int e = blockIdx.x * 256 + threadIdx.x;
    if (e >= NE) return;
    int w = flag[0];
    int dst = w ? ei[2 * (NE + e)] : ei[NE + e];
    atomicAdd(&deg[dst], 1);
}

__global__ void k_scan1(const int* __restrict__ cnt, int* __restrict__ offs,
                        int* __restrict__ chunks)
{
    __shared__ int sd[256];
    int t = threadIdx.x;
    int base = blockIdx.x * SCAN_CHUNK + t * 8;
    int v[8];
    int s = 0;
    #pragma unroll
    for (int i = 0; i < 8; ++i) {
        int idx = base + i;
        v[i] = (idx < NN) ? cnt[idx] : 0;
        s += v[i];
    }
    sd[t] = s;
    __syncthreads();
    for (int o = 1; o < 256; o <<= 1) {
        int x = (t >= o) ? sd[t - o] : 0;
        __syncthreads();
        sd[t] += x;
        __syncthreads();
    }
    int run = sd[t] - s;  // exclusive prefix of this thread within chunk
    if (t == 255) chunks[blockIdx.x] = sd[255];
    #pragma unroll
    for (int i = 0; i < 8; ++i) {
        int idx = base + i;
        if (idx < NN) offs[idx] = run;
        run += v[i];
    }
}

__global__ void k_scan2(int* __restrict__ chunks, int* __restrict__ offs)
{
    if (threadIdx.x == 0 && blockIdx.x == 0) {
        int run = 0;
        for (int c = 0; c < NCHUNK; ++c) {
            int v = chunks[c];
            chunks[c] = run;
            run += v;
        }
        offs[NN] = run;  // == NE
    }
}

__global__ void k_add2(int* __restrict__ offs, const int* __restrict__ chunks,
                       int* __restrict__ cursor, const int* __restrict__ deg,
                       float* __restrict__ deginv)
{
    int i = blockIdx.x * 256 + threadIdx.x;
    if (i >= NN) return;
    int v = offs[i] + chunks[i >> 11];  // SCAN_CHUNK == 2048
    offs[i] = v;
    cursor[i] = v;
    int d = deg[i];
    deginv[i] = (d > 0) ? 1.0f / (float)d : 0.0f;
}

__global__ void k_fill(const int* __restrict__ ei, const int* __restrict__ flag,
                       int* __restrict__ cursor, int* __restrict__ csr)
{
    int e = blockIdx.x * 256 + threadIdx.x;
    if (e >= NE) return;
    int w = flag[0];
    int src = w ? ei[2 * e] : ei[e];
    int dst = w ? ei[2 * (NE + e)] : ei[NE + e];
    int p = atomicAdd(&cursor[dst], 1);
    csr[p] = src;
}

// Fold BN scale into weights: w2[l][j][k] (k<128: lin_l, k>=128: lin_r), bias folded too.
__global__ void k_fold(const float* __restrict__ lwl, const float* __restrict__ lbl,
                       const float* __restrict__ lwr, const float* __restrict__ bnw,
                       const float* __restrict__ bnb, float* __restrict__ w2,
                       float* __restrict__ bias)
{
    int id = blockIdx.x * 256 + threadIdx.x;  // 3*128*256 total
    int l = id >> 15;
    int j = (id >> 8) & 127;
    int k = id & 255;
    float inv_std = 1.0f / sqrtf(1.0f + 1e-5f);
    float s = inv_std * bnw[l * 128 + j];
    float w = (k < 128) ? lwl[(l * 128 + j) * 128 + k]
                        : lwr[(l * 128 + j) * 128 + (k - 128)];
    w2[id] = w * s;  // id == (l*128 + j)*256 + k
    if (k == 0) bias[l * 128 + j] = lbl[l * 128 + j] * s + bnb[l * 128 + j];
}

__global__ void k_colsum(const float* __restrict__ x, float* __restrict__ gsum)
{
    int c = threadIdx.x;  // 128 threads
    float s = 0.f;
    for (int r = blockIdx.x; r < NN; r += gridDim.x)
        s += x[(size_t)r * 128 + c];
    atomicAdd(&gsum[c], s);
}

// One wave per destination node: gather-mean of in[src] rows.
__global__ void k_gather(const float* __restrict__ in, const int* __restrict__ offs,
                         const int* __restrict__ csr, const float* __restrict__ deginv,
                         float* __restrict__ agg)
{
    int wave = (blockIdx.x * 256 + threadIdx.x) >> 6;
    int lane = threadIdx.x & 63;
    if (wave >= NN) return;
    int s = offs[wave], e = offs[wave + 1];
    float ax = 0.f, ay = 0.f;
    const float2* base = (const float2*)in;
    for (int i = s; i < e; ++i) {
        int src = csr[i];
        float2 v = base[(size_t)src * 64 + lane];
        ax += v.x;
        ay += v.y;
    }
    float di = deginv[wave];
    float2 o;
    o.x = ax * di;
    o.y = ay * di;
    ((float2*)agg)[(size_t)wave * 64 + lane] = o;
}

// Fused combine: out = relu( [agg | in] @ w2^T + bias ); writes h (optional) and
// accumulates column sums into gsum. 128 rows/block, 8x8 micro-tile, 256 thr.
__global__ __launch_bounds__(256, 2)
void k_combine(const float* __restrict__ agg, const float* __restrict__ in,
               const float* __restrict__ w2, const float* __restrict__ bias,
               float* __restrict__ hout, float* __restrict__ gsum, int write_h)
{
    __shared__ float As[128 * 64];
    __shared__ float Ws[128 * 64];
    const int tid = threadIdx.x;
    const int tx = tid & 15, ty = tid >> 4;
    const int c0 = tx * 8, r0 = ty * 8;
    const int rowbase = blockIdx.x * 128;

    float acc[8][8];
    #pragma unroll
    for (int i = 0; i < 8; ++i)
        #pragma unroll
        for (int j = 0; j < 8; ++j) acc[i][j] = 0.f;

    const int swA = (ty & 7) << 2;
    const int swW = (tx & 7) << 2;
    const int swAW = swA ^ swW;
    const int kq = tid & 15;
    const int rb = tid >> 4;

    for (int part = 0; part < 4; ++part) {
        const float* asrc = (part < 2) ? agg : in;
        const int k0 = (part & 1) * 64;   // column chunk within the 128-wide source
        const int kg = part * 64;         // chunk within the 256-wide concat / W

        #pragma unroll
        for (int p = 0; p < 8; ++p) {
            int r = rb + p * 16;          // 0..127 (rows of A tile == rows j of W)
            int row = rowbase + r;
            float4 va = make_float4(0.f, 0.f, 0.f, 0.f);
            if (row < NN)
                va = *(const float4*)(asrc + (size_t)row * 128 + k0 + kq * 4);
            int sw = ((r >> 3) & 7) << 2;
            *(float4*)&As[r * 64 + ((kq * 4) ^ sw)] = va;
            float4 vw = *(const float4*)(w2 + (size_t)r * 256 + kg + kq * 4);
            *(float4*)&Ws[r * 64 + ((kq * 4) ^ sw)] = vw;
        }
        __syncthreads();

        #pragma unroll 4
        for (int ka = 0; ka < 64; ka += 4) {
            const int kw = ka ^ swAW;
            float4 a[8], w[8];
            #pragma unroll
            for (int i = 0; i < 8; ++i)
                a[i] = *(const float4*)&As[(r0 + i) * 64 + ka];
            #pragma unroll
            for (int j = 0; j < 8; ++j)
                w[j] = *(const float4*)&Ws[(c0 + j) * 64 + kw];
            #pragma unroll
            for (int i = 0; i < 8; ++i)
                #pragma unroll
                for (int j = 0; j < 8; ++j) {
                    acc[i][j] = fmaf(a[i].x, w[j].x, acc[i][j]);
                    acc[i][j] = fmaf(a[i].y, w[j].y, acc[i][j]);
                    acc[i][j] = fmaf(a[i].z, w[j].z, acc[i][j]);
                    acc[i][j] = fmaf(a[i].w, w[j].w, acc[i][j]);
                }
        }
        __syncthreads();
    }

    float b[8];
    #pragma unroll
    for (int j = 0; j < 8; ++j) b[j] = bias[c0 + j];

    float col[8];
    #pragma unroll
    for (int j = 0; j < 8; ++j) col[j] = 0.f;

    #pragma unroll
    for (int i = 0; i < 8; ++i) {
        int row = rowbase + r0 + i;
        bool ok = row < NN;
        float o[8];
        #pragma unroll
        for (int j = 0; j < 8; ++j) {
            o[j] = frelu(acc[i][j] + b[j]);
            if (ok) col[j] += o[j];
        }
        if (ok && write_h) {
            *(float4*)(hout + (size_t)row * 128 + c0) =
                make_float4(o[0], o[1], o[2], o[3]);
            *(float4*)(hout + (size_t)row * 128 + c0 + 4) =
                make_float4(o[4], o[5], o[6], o[7]);
        }
    }

    __syncthreads();
    // reuse As as [16][128] reduction buffer
    #pragma unroll
    for (int j = 0; j < 8; ++j) As[ty * 128 + c0 + j] = col[j];
    __syncthreads();
    int cc = tid & 127, half = tid >> 7;
    float s = 0.f;
    #pragma unroll
    for (int t = 0; t < 8; ++t) s += As[(half * 8 + t) * 128 + cc];
    atomicAdd(&gsum[cc], s);
}

__global__ void k_mlp(const float* __restrict__ gsum,
                      const float* __restrict__ fc1w, const float* __restrict__ fc1b,
                      const float* __restrict__ fc2w, const float* __restrict__ fc2b,
                      const float* __restrict__ fc3w, const float* __restrict__ fc3b,
                      float* __restrict__ out)
{
    __shared__ float g[128], t1[256], t2[128];
    int t = threadIdx.x;
    if (t < 128) g[t] = gsum[t];
    __syncthreads();
    float a = fc1b[t];
    for (int k = 0; k < 128; ++k) a += fc1w[t * 128 + k] * g[k];
    t1[t] = frelu(a);
    __syncthreads();
    if (t < 128) {
        float a2 = fc2b[t];
        for (int k = 0; k < 256; ++k) a2 += fc2w[t * 256 + k] * t1[k];
        t2[t] = frelu(a2);
    }
    __syncthreads();
    if (t < 64) {
        float s = t2[t] * fc3w[t] + t2[t + 64] * fc3w[t + 64];
        for (int o = 32; o; o >>= 1) s += __shfl_down(s, o);
        if (t == 0) out[0] = s + fc3b[0];
    }
}

extern "C" void kernel_launch(void* const* d_in, const int* in_sizes, int n_in,
                              void* d_out, int out_size, void* d_ws, size_t ws_size,
                              hipStream_t stream)
{
    const float* x    = (const float*)d_in[0];
    const int*   ei   = (const int*)d_in[1];
    const float* lwl  = (const float*)d_in[2];
    const float* lbl  = (const float*)d_in[3];
    const float* lwr  = (const float*)d_in[4];
    const float* bnw  = (const float*)d_in[5];
    const float* bnb  = (const float*)d_in[6];
    const float* fc1w = (const float*)d_in[7];
    const float* fc1b = (const float*)d_in[8];
    const float* fc2w = (const float*)d_in[9];
    const float* fc2b = (const float*)d_in[10];
    const float* fc3w = (const float*)d_in[11];
    const float* fc3b = (const float*)d_in[12];
    float* out = (float*)d_out;

    char* ws = (char*)d_ws;
    size_t off = 0;
    auto alloc = [&](size_t b) -> char* {
        char* p = ws + off;
        off = (off + b + 255) & ~(size_t)255;
        return p;
    };
    int*   deg_cnt = (int*)alloc((size_t)NN * 4);
    int*   offs    = (int*)alloc((size_t)(NN + 1) * 4);
    int*   cursor  = (int*)alloc((size_t)NN * 4);
    int*   chunks  = (int*)alloc(64 * 4);
    int*   csr     = (int*)alloc((size_t)NE * 4);
    int*   flag    = (int*)alloc(4);
    float* deginv  = (float*)alloc((size_t)NN * 4);
    float* w2      = (float*)alloc((size_t)3 * 128 * 256 * 4);
    float* bias    = (float*)alloc((size_t)3 * 128 * 4);
    float* gsum    = (float*)alloc(128 * 4);
    float* h       = (float*)alloc((size_t)NN * 128 * 4);
    float* agg     = (float*)alloc((size_t)NN * 128 * 4);

    hipMemsetAsync(deg_cnt, 0, (size_t)NN * 4, stream);
    hipMemsetAsync(gsum, 0, 128 * 4, stream);

    k_detect<<<1, 64, 0, stream>>>(ei, flag);
    k_count<<<(NE + 255) / 256, 256, 0, stream>>>(ei, flag, deg_cnt);
    k_scan1<<<NCHUNK, 256, 0, stream>>>(deg_cnt, offs, chunks);
    k_scan2<<<1, 64, 0, stream>>>(chunks, offs);
    k_add2<<<(NN + 255) / 256, 256, 0, stream>>>(offs, chunks, cursor, deg_cnt, deginv);
    k_fill<<<(NE + 255) / 256, 256, 0, stream>>>(ei, flag, cursor, csr);
    k_fold<<<(3 * 128 * 256) / 256, 256, 0, stream>>>(lwl, lbl, lwr, bnw, bnb, w2, bias);
    k_colsum<<<512, 128, 0, stream>>>(x, gsum);

    const float* hin = x;
    for (int l = 0; l < 3; ++l) {
        k_gather<<<(NN * 64) / 256, 256, 0, stream>>>(hin, offs, csr, deginv, agg);
        k_combine<<<(NN + 127) / 128, 256, 0, stream>>>(
            agg, hin, w2 + (size_t)l * 128 * 256, bias + (size_t)l * 128,
            h, gsum, (l < 2) ? 1 : 0);
        hin = h;
    }
    k_mlp<<<1, 256, 0, stream>>>(gsum, fc1w, fc1b, fc2w, fc2b, fc3w, fc3b, out);
}

// Round 2
// 530.677 us; speedup vs baseline: 1.4626x; 1.4626x over previous
//
#include <hip/hip_runtime.h>

#define NN 100000
#define NE 600000
#define DD 128
#define SCAN_CHUNK 2048
#define NCHUNK 49  /* ceil(NN / SCAN_CHUNK) */

typedef __attribute__((ext_vector_type(8))) short bf8;
typedef __attribute__((ext_vector_type(4))) float f4;
typedef __attribute__((ext_vector_type(4))) unsigned short us4;
typedef __attribute__((ext_vector_type(8))) unsigned short us8;

__device__ __forceinline__ float frelu(float x) { return x > 0.f ? x : 0.f; }

__device__ __forceinline__ float b2f(unsigned short u)
{
    union { unsigned int i; float f; } c;
    c.i = ((unsigned int)u) << 16;
    return c.f;
}

__device__ __forceinline__ unsigned short f2b(float f)
{
    union { float f; unsigned int i; } c;
    c.f = f;
    unsigned int u = c.i;
    return (unsigned short)((u + 0x7fffu + ((u >> 16) & 1u)) >> 16);
}

// ---- edge_index dtype detector: int64 (little-endian) => odd words all zero ----
__global__ void k_detect(const int* __restrict__ ei, int* __restrict__ flag)
{
    if (blockIdx.x == 0 && threadIdx.x == 0) {
        int z = 1;
        for (int i = 0; i < 64; ++i)
            if (ei[2 * i + 1] != 0) { z = 0; break; }
        flag[0] = z;
    }
}

__global__ void k_count(const int* __restrict__ ei, const int* __restrict__ flag,
                        int* __restrict__ deg)
{
    int e = blockIdx.x * 256 + threadIdx.x;
    if (e >= NE) return;
    int w = flag[0];
    int dst = w ? ei[2 * (NE + e)] : ei[NE + e];
    atomicAdd(&deg[dst], 1);
}

__global__ void k_scan1(const int* __restrict__ cnt, int* __restrict__ offs,
                        int* __restrict__ chunks)
{
    __shared__ int sd[256];
    int t = threadIdx.x;
    int base = blockIdx.x * SCAN_CHUNK + t * 8;
    int v[8];
    int s = 0;
    #pragma unroll
    for (int i = 0; i < 8; ++i) {
        int idx = base + i;
        v[i] = (idx < NN) ? cnt[idx] : 0;
        s += v[i];
    }
    sd[t] = s;
    __syncthreads();
    for (int o = 1; o < 256; o <<= 1) {
        int x = (t >= o) ? sd[t - o] : 0;
        __syncthreads();
        sd[t] += x;
        __syncthreads();
    }
    int run = sd[t] - s;
    if (t == 255) chunks[blockIdx.x] = sd[255];
    #pragma unroll
    for (int i = 0; i < 8; ++i) {
        int idx = base + i;
        if (idx < NN) offs[idx] = run;
        run += v[i];
    }
}

__global__ void k_scan2(int* __restrict__ chunks, int* __restrict__ offs)
{
    if (threadIdx.x == 0 && blockIdx.x == 0) {
        int run = 0;
        for (int c = 0; c < NCHUNK; ++c) {
            int v = chunks[c];
            chunks[c] = run;
            run += v;
        }
        offs[NN] = run;
    }
}

__global__ void k_add2(int* __restrict__ offs, const int* __restrict__ chunks,
                       int* __restrict__ cursor, const int* __restrict__ deg,
                       float* __restrict__ deginv)
{
    int i = blockIdx.x * 256 + threadIdx.x;
    if (i >= NN) return;
    int v = offs[i] + chunks[i >> 11];
    offs[i] = v;
    cursor[i] = v;
    int d = deg[i];
    deginv[i] = (d > 0) ? 1.0f / (float)d : 0.0f;
}

__global__ void k_fill(const int* __restrict__ ei, const int* __restrict__ flag,
                       int* __restrict__ cursor, int* __restrict__ csr)
{
    int e = blockIdx.x * 256 + threadIdx.x;
    if (e >= NE) return;
    int w = flag[0];
    int src = w ? ei[2 * e] : ei[e];
    int dst = w ? ei[2 * (NE + e)] : ei[NE + e];
    int p = atomicAdd(&cursor[dst], 1);
    csr[p] = src;
}

// Fold BN into weights, emit bf16 W2[l][j][k] (k<128: lin_l, k>=128: lin_r) + fp32 bias.
__global__ void k_fold(const float* __restrict__ lwl, const float* __restrict__ lbl,
                       const float* __restrict__ lwr, const float* __restrict__ bnw,
                       const float* __restrict__ bnb, unsigned short* __restrict__ w2,
                       float* __restrict__ bias)
{
    int id = blockIdx.x * 256 + threadIdx.x;  // 3*128*256 total
    int l = id >> 15;
    int j = (id >> 8) & 127;
    int k = id & 255;
    float inv_std = 1.0f / sqrtf(1.0f + 1e-5f);
    float s = inv_std * bnw[l * 128 + j];
    float w = (k < 128) ? lwl[(l * 128 + j) * 128 + k]
                        : lwr[(l * 128 + j) * 128 + (k - 128)];
    w2[id] = f2b(w * s);
    if (k == 0) bias[l * 128 + j] = lbl[l * 128 + j] * s + bnb[l * 128 + j];
}

// fp32 x -> bf16 copy (8 elems/thread)
__global__ void k_cvt(const float* __restrict__ x, unsigned short* __restrict__ xb)
{
    int idx = blockIdx.x * 256 + threadIdx.x;  // 1.6M threads exactly
    const float4* x4 = (const float4*)x;
    float4 a = x4[idx * 2];
    float4 b = x4[idx * 2 + 1];
    us8 o;
    o[0] = f2b(a.x); o[1] = f2b(a.y); o[2] = f2b(a.z); o[3] = f2b(a.w);
    o[4] = f2b(b.x); o[5] = f2b(b.y); o[6] = f2b(b.z); o[7] = f2b(b.w);
    *(us8*)(xb + (size_t)idx * 8) = o;
}

__global__ void k_colsum(const float* __restrict__ x, float* __restrict__ gsum)
{
    int c = threadIdx.x;  // 128 threads
    float s = 0.f;
    for (int r = blockIdx.x; r < NN; r += gridDim.x)
        s += x[(size_t)r * 128 + c];
    atomicAdd(&gsum[c], s);
}

// One wave per destination node: gather-mean of bf16 rows (4 B/lane).
__global__ void k_gather(const unsigned short* __restrict__ in,
                         const int* __restrict__ offs, const int* __restrict__ csr,
                         const float* __restrict__ deginv,
                         unsigned short* __restrict__ agg)
{
    int wave = (blockIdx.x * 256 + threadIdx.x) >> 6;
    int lane = threadIdx.x & 63;
    if (wave >= NN) return;
    int s = offs[wave], e = offs[wave + 1];
    float ax = 0.f, ay = 0.f;
    const unsigned int* base = (const unsigned int*)in;
    for (int i = s; i < e; ++i) {
        int src = csr[i];
        unsigned int v = base[(size_t)src * 64 + lane];
        ax += b2f((unsigned short)(v & 0xffffu));
        ay += b2f((unsigned short)(v >> 16));
    }
    float di = deginv[wave];
    unsigned int o = (unsigned int)f2b(ax * di) | ((unsigned int)f2b(ay * di) << 16);
    ((unsigned int*)agg)[(size_t)wave * 64 + lane] = o;
}

// MFMA combine: out = relu([agg|hin] @ W2^T + bias), h out in bf16, colsum into gsum.
// 256 thr = 4 waves, 64 rows/block, each wave 16 rows x 128 channels.
__global__ __launch_bounds__(256, 2)
void k_combine(const unsigned short* __restrict__ aggb,
               const unsigned short* __restrict__ hinb,
               const unsigned short* __restrict__ w2, const float* __restrict__ bias,
               unsigned short* __restrict__ hout, float* __restrict__ gsum, int write_h)
{
    __shared__ unsigned short sW[128 * 256];  // 64 KB, XOR-swizzled 16B chunks
    const int tid = threadIdx.x;
    const int lane = tid & 63, wid = tid >> 6;

    // stage W2 layer (64 KB) into LDS with swizzle: chunk c of row j at (c*16)^((j&7)<<4)
    {
        const f4* wg = (const f4*)w2;
        #pragma unroll
        for (int it = 0; it < 16; ++it) {
            int idx = it * 256 + tid;       // 0..4095 chunks
            int j = idx >> 5, c = idx & 31;
            f4 v = wg[idx];
            *(f4*)((char*)sW + j * 512 + ((c * 16) ^ ((j & 7) << 4))) = v;
        }
    }
    __syncthreads();

    const int r15 = lane & 15, q = lane >> 4;
    const int row = blockIdx.x * 64 + wid * 16 + r15;
    const int rowc = (row < NN) ? row : (NN - 1);
    const bool ok = row < NN;

    f4 acc[8];
    #pragma unroll
    for (int ct = 0; ct < 8; ++ct) acc[ct] = (f4){0.f, 0.f, 0.f, 0.f};

    #pragma unroll
    for (int ks = 0; ks < 8; ++ks) {
        const unsigned short* s = (ks < 4) ? aggb : hinb;
        bf8 bfrag = *(const bf8*)(s + (size_t)rowc * 128 + (ks & 3) * 32 + q * 8);
        #pragma unroll
        for (int ct = 0; ct < 8; ++ct) {
            int j = ct * 16 + r15;
            bf8 wfrag = *(const bf8*)((char*)sW + j * 512 +
                                      ((ks * 64 + q * 16) ^ ((j & 7) << 4)));
            acc[ct] = __builtin_amdgcn_mfma_f32_16x16x32_bf16(wfrag, bfrag, acc[ct], 0, 0, 0);
        }
    }

    // epilogue: bias + relu (+zero OOB), store bf16, column sums
    #pragma unroll
    for (int ct = 0; ct < 8; ++ct) {
        f4 o;
        #pragma unroll
        for (int r = 0; r < 4; ++r) {
            float v = acc[ct][r] + bias[ct * 16 + q * 4 + r];
            v = frelu(v);
            o[r] = ok ? v : 0.f;
        }
        acc[ct] = o;
        if (ok && write_h) {
            us4 p;
            p[0] = f2b(o[0]); p[1] = f2b(o[1]); p[2] = f2b(o[2]); p[3] = f2b(o[3]);
            *(us4*)(hout + (size_t)row * 128 + ct * 16 + q * 4) = p;
        }
    }

    // reduce over the 16 rows (lanes r15) per q-group
    #pragma unroll
    for (int ct = 0; ct < 8; ++ct)
        #pragma unroll
        for (int r = 0; r < 4; ++r) {
            float v = acc[ct][r];
            v += __shfl_xor(v, 1);
            v += __shfl_xor(v, 2);
            v += __shfl_xor(v, 4);
            v += __shfl_xor(v, 8);
            acc[ct][r] = v;
        }

    __syncthreads();  // sW no longer needed as weights
    float* red = (float*)sW;
    if (r15 == 0) {
        #pragma unroll
        for (int ct = 0; ct < 8; ++ct)
            #pragma unroll
            for (int r = 0; r < 4; ++r)
                red[wid * 128 + ct * 16 + q * 4 + r] = acc[ct][r];
    }
    __syncthreads();
    if (tid < 128) {
        float s = red[tid] + red[128 + tid] + red[256 + tid] + red[384 + tid];
        atomicAdd(&gsum[tid], s);
    }
}

__global__ void k_mlp(const float* __restrict__ gsum,
                      const float* __restrict__ fc1w, const float* __restrict__ fc1b,
                      const float* __restrict__ fc2w, const float* __restrict__ fc2b,
                      const float* __restrict__ fc3w, const float* __restrict__ fc3b,
                      float* __restrict__ out)
{
    __shared__ float g[128], t1[256], t2[128];
    int t = threadIdx.x;
    if (t < 128) g[t] = gsum[t];
    __syncthreads();
    float a = fc1b[t];
    for (int k = 0; k < 128; ++k) a += fc1w[t * 128 + k] * g[k];
    t1[t] = frelu(a);
    __syncthreads();
    if (t < 128) {
        float a2 = fc2b[t];
        for (int k = 0; k < 256; ++k) a2 += fc2w[t * 256 + k] * t1[k];
        t2[t] = frelu(a2);
    }
    __syncthreads();
    if (t < 64) {
        float s = t2[t] * fc3w[t] + t2[t + 64] * fc3w[t + 64];
        for (int o = 32; o; o >>= 1) s += __shfl_down(s, o);
        if (t == 0) out[0] = s + fc3b[0];
    }
}

extern "C" void kernel_launch(void* const* d_in, const int* in_sizes, int n_in,
                              void* d_out, int out_size, void* d_ws, size_t ws_size,
                              hipStream_t stream)
{
    const float* x    = (const float*)d_in[0];
    const int*   ei   = (const int*)d_in[1];
    const float* lwl  = (const float*)d_in[2];
    const float* lbl  = (const float*)d_in[3];
    const float* lwr  = (const float*)d_in[4];
    const float* bnw  = (const float*)d_in[5];
    const float* bnb  = (const float*)d_in[6];
    const float* fc1w = (const float*)d_in[7];
    const float* fc1b = (const float*)d_in[8];
    const float* fc2w = (const float*)d_in[9];
    const float* fc2b = (const float*)d_in[10];
    const float* fc3w = (const float*)d_in[11];
    const float* fc3b = (const float*)d_in[12];
    float* out = (float*)d_out;

    char* ws = (char*)d_ws;
    size_t off = 0;
    auto alloc = [&](size_t b) -> char* {
        char* p = ws + off;
        off = (off + b + 255) & ~(size_t)255;
        return p;
    };
    int*   deg_cnt = (int*)alloc((size_t)NN * 4);
    int*   offs    = (int*)alloc((size_t)(NN + 1) * 4);
    int*   cursor  = (int*)alloc((size_t)NN * 4);
    int*   chunks  = (int*)alloc(64 * 4);
    int*   csr     = (int*)alloc((size_t)NE * 4);
    int*   flag    = (int*)alloc(4);
    float* deginv  = (float*)alloc((size_t)NN * 4);
    unsigned short* w2   = (unsigned short*)alloc((size_t)3 * 128 * 256 * 2);
    float* bias    = (float*)alloc((size_t)3 * 128 * 4);
    float* gsum    = (float*)alloc(128 * 4);
    unsigned short* xbf  = (unsigned short*)alloc((size_t)NN * 128 * 2);
    unsigned short* h    = (unsigned short*)alloc((size_t)NN * 128 * 2);
    unsigned short* agg  = (unsigned short*)alloc((size_t)NN * 128 * 2);

    hipMemsetAsync(deg_cnt, 0, (size_t)NN * 4, stream);
    hipMemsetAsync(gsum, 0, 128 * 4, stream);

    k_detect<<<1, 64, 0, stream>>>(ei, flag);
    k_count<<<(NE + 255) / 256, 256, 0, stream>>>(ei, flag, deg_cnt);
    k_scan1<<<NCHUNK, 256, 0, stream>>>(deg_cnt, offs, chunks);
    k_scan2<<<1, 64, 0, stream>>>(chunks, offs);
    k_add2<<<(NN + 255) / 256, 256, 0, stream>>>(offs, chunks, cursor, deg_cnt, deginv);
    k_fill<<<(NE + 255) / 256, 256, 0, stream>>>(ei, flag, cursor, csr);
    k_fold<<<(3 * 128 * 256) / 256, 256, 0, stream>>>(lwl, lbl, lwr, bnw, bnb, w2, bias);
    k_cvt<<<(NN * 128 / 8) / 256, 256, 0, stream>>>(x, xbf);
    k_colsum<<<512, 128, 0, stream>>>(x, gsum);

    const unsigned short* hin = xbf;
    for (int l = 0; l < 3; ++l) {
        k_gather<<<(NN * 64) / 256, 256, 0, stream>>>(hin, offs, csr, deginv, agg);
        k_combine<<<(NN + 63) / 64, 256, 0, stream>>>(
            agg, hin, w2 + (size_t)l * 128 * 256, bias + (size_t)l * 128,
            h, gsum, (l < 2) ? 1 : 0);
        hin = h;
    }
    k_mlp<<<1, 256, 0, stream>>>(gsum, fc1w, fc1b, fc2w, fc2b, fc3w, fc3b, out);
}

// Round 3
// 301.062 us; speedup vs baseline: 2.5780x; 1.7627x over previous
//
#include <hip/hip_runtime.h>

#define NN 100000
#define NE 600000
#define DD 128
#define SCAN_CHUNK 2048
#define NCHUNK 49  /* ceil(NN / SCAN_CHUNK) */

typedef __attribute__((ext_vector_type(8))) short bf8;
typedef __attribute__((ext_vector_type(4))) float f4;
typedef __attribute__((ext_vector_type(4))) unsigned short us4;
typedef __attribute__((ext_vector_type(8))) unsigned short us8;

__device__ __forceinline__ float frelu(float x) { return x > 0.f ? x : 0.f; }

__device__ __forceinline__ float b2f(unsigned short u)
{
    union { unsigned int i; float f; } c;
    c.i = ((unsigned int)u) << 16;
    return c.f;
}

__device__ __forceinline__ unsigned short f2b(float f)
{
    union { float f; unsigned int i; } c;
    c.f = f;
    unsigned int u = c.i;
    return (unsigned short)((u + 0x7fffu + ((u >> 16) & 1u)) >> 16);
}

// ---- edge_index dtype detector: int64 (little-endian) => odd words all zero ----
__global__ void k_detect(const int* __restrict__ ei, int* __restrict__ flag)
{
    if (blockIdx.x == 0 && threadIdx.x == 0) {
        int z = 1;
        for (int i = 0; i < 64; ++i)
            if (ei[2 * i + 1] != 0) { z = 0; break; }
        flag[0] = z;
    }
}

__global__ void k_count(const int* __restrict__ ei, const int* __restrict__ flag,
                        int* __restrict__ deg)
{
    int e = blockIdx.x * 256 + threadIdx.x;
    if (e >= NE) return;
    int w = flag[0];
    int dst = w ? ei[2 * (NE + e)] : ei[NE + e];
    atomicAdd(&deg[dst], 1);
}

__global__ void k_scan1(const int* __restrict__ cnt, int* __restrict__ offs,
                        int* __restrict__ chunks)
{
    __shared__ int sd[256];
    int t = threadIdx.x;
    int base = blockIdx.x * SCAN_CHUNK + t * 8;
    int v[8];
    int s = 0;
    #pragma unroll
    for (int i = 0; i < 8; ++i) {
        int idx = base + i;
        v[i] = (idx < NN) ? cnt[idx] : 0;
        s += v[i];
    }
    sd[t] = s;
    __syncthreads();
    for (int o = 1; o < 256; o <<= 1) {
        int x = (t >= o) ? sd[t - o] : 0;
        __syncthreads();
        sd[t] += x;
        __syncthreads();
    }
    int run = sd[t] - s;
    if (t == 255) chunks[blockIdx.x] = sd[255];
    #pragma unroll
    for (int i = 0; i < 8; ++i) {
        int idx = base + i;
        if (idx < NN) offs[idx] = run;
        run += v[i];
    }
}

__global__ void k_scan2(int* __restrict__ chunks, int* __restrict__ offs)
{
    if (threadIdx.x == 0 && blockIdx.x == 0) {
        int run = 0;
        for (int c = 0; c < NCHUNK; ++c) {
            int v = chunks[c];
            chunks[c] = run;
            run += v;
        }
        offs[NN] = run;
    }
}

__global__ void k_add2(int* __restrict__ offs, const int* __restrict__ chunks,
                       int* __restrict__ cursor, const int* __restrict__ deg,
                       float* __restrict__ deginv)
{
    int i = blockIdx.x * 256 + threadIdx.x;
    if (i >= NN) return;
    int v = offs[i] + chunks[i >> 11];
    offs[i] = v;
    cursor[i] = v;
    int d = deg[i];
    deginv[i] = (d > 0) ? 1.0f / (float)d : 0.0f;
}

__global__ void k_fill(const int* __restrict__ ei, const int* __restrict__ flag,
                       int* __restrict__ cursor, int* __restrict__ csr)
{
    int e = blockIdx.x * 256 + threadIdx.x;
    if (e >= NE) return;
    int w = flag[0];
    int src = w ? ei[2 * e] : ei[e];
    int dst = w ? ei[2 * (NE + e)] : ei[NE + e];
    int p = atomicAdd(&cursor[dst], 1);
    csr[p] = src;
}

// Fold BN into weights, emit bf16 W2[l][j][k] (k<128: lin_l, k>=128: lin_r) + fp32 bias.
__global__ void k_fold(const float* __restrict__ lwl, const float* __restrict__ lbl,
                       const float* __restrict__ lwr, const float* __restrict__ bnw,
                       const float* __restrict__ bnb, unsigned short* __restrict__ w2,
                       float* __restrict__ bias)
{
    int id = blockIdx.x * 256 + threadIdx.x;  // 3*128*256 total
    int l = id >> 15;
    int j = (id >> 8) & 127;
    int k = id & 255;
    float inv_std = 1.0f / sqrtf(1.0f + 1e-5f);
    float s = inv_std * bnw[l * 128 + j];
    float w = (k < 128) ? lwl[(l * 128 + j) * 128 + k]
                        : lwr[(l * 128 + j) * 128 + (k - 128)];
    w2[id] = f2b(w * s);
    if (k == 0) bias[l * 128 + j] = lbl[l * 128 + j] * s + bnb[l * 128 + j];
}

// Fused fp32->bf16 convert + column sum. 256 thr: 16 row-groups x 16 col-octets.
__global__ void k_cvtsum(const float* __restrict__ x, unsigned short* __restrict__ xb,
                         float* __restrict__ gsum)
{
    __shared__ float red[16][128];
    const int t = threadIdx.x;
    const int c8 = (t & 15) * 8;
    const int rg = t >> 4;
    float s[8];
    #pragma unroll
    for (int j = 0; j < 8; ++j) s[j] = 0.f;
    for (int r = blockIdx.x * 16 + rg; r < NN; r += gridDim.x * 16) {
        const f4* p = (const f4*)(x + (size_t)r * 128 + c8);
        f4 a = p[0], b = p[1];
        us8 o;
        o[0] = f2b(a[0]); o[1] = f2b(a[1]); o[2] = f2b(a[2]); o[3] = f2b(a[3]);
        o[4] = f2b(b[0]); o[5] = f2b(b[1]); o[6] = f2b(b[2]); o[7] = f2b(b[3]);
        *(us8*)(xb + (size_t)r * 128 + c8) = o;
        s[0] += a[0]; s[1] += a[1]; s[2] += a[2]; s[3] += a[3];
        s[4] += b[0]; s[5] += b[1]; s[6] += b[2]; s[7] += b[3];
    }
    #pragma unroll
    for (int j = 0; j < 8; ++j) red[rg][c8 + j] = s[j];
    __syncthreads();
    if (t < 128) {
        float v = 0.f;
        #pragma unroll
        for (int g = 0; g < 16; ++g) v += red[g][t];
        atomicAdd(&gsum[t], v);
    }
}

// One wave per destination node, 4 edges per iteration (16 lanes / row, 16B each).
__global__ void k_gather(const unsigned short* __restrict__ in,
                         const int* __restrict__ offs, const int* __restrict__ csr,
                         const float* __restrict__ deginv,
                         unsigned short* __restrict__ agg)
{
    int wave = (blockIdx.x * 256 + threadIdx.x) >> 6;
    int lane = threadIdx.x & 63;
    if (wave >= NN) return;
    int s = offs[wave], e = offs[wave + 1];
    const int g = lane >> 4;          // edge sub-group 0..3
    const int c8 = (lane & 15) * 8;   // channel octet
    float acc[8];
    #pragma unroll
    for (int j = 0; j < 8; ++j) acc[j] = 0.f;
    for (int i = s + g; i < e; i += 4) {
        int src = csr[i];
        us8 v = *(const us8*)(in + (size_t)src * 128 + c8);
        #pragma unroll
        for (int j = 0; j < 8; ++j) acc[j] += b2f(v[j]);
    }
    // reduce across the 4 edge groups (lanes differing in bits 4,5)
    #pragma unroll
    for (int j = 0; j < 8; ++j) {
        float v = acc[j];
        v += __shfl_xor(v, 16);
        v += __shfl_xor(v, 32);
        acc[j] = v;
    }
    if (lane < 16) {
        float di = deginv[wave];
        us8 o;
        #pragma unroll
        for (int j = 0; j < 8; ++j) o[j] = f2b(acc[j] * di);
        *(us8*)(agg + (size_t)wave * 128 + c8) = o;
    }
}

// MFMA combine: out = relu([agg|hin] @ W2^T + bias), h out bf16, colsum into gsum.
// 256 thr = 4 waves; block covers 256 rows in 4 groups of 64; W staged once.
__global__ __launch_bounds__(256, 2)
void k_combine(const unsigned short* __restrict__ aggb,
               const unsigned short* __restrict__ hinb,
               const unsigned short* __restrict__ w2, const float* __restrict__ bias,
               unsigned short* __restrict__ hout, float* __restrict__ gsum, int write_h)
{
    __shared__ unsigned short sW[128 * 256];  // 64 KB, XOR-swizzled 16B chunks
    __shared__ float red[512];
    const int tid = threadIdx.x;
    const int lane = tid & 63, wid = tid >> 6;

    // stage W2 layer (64 KB) into LDS: chunk c of row j at (c*16)^((j&7)<<4)
    {
        const f4* wg = (const f4*)w2;
        #pragma unroll
        for (int it = 0; it < 16; ++it) {
            int idx = it * 256 + tid;       // 0..4095 chunks
            int j = idx >> 5, c = idx & 31;
            f4 v = wg[idx];
            *(f4*)((char*)sW + j * 512 + ((c * 16) ^ ((j & 7) << 4))) = v;
        }
    }
    __syncthreads();

    const int r15 = lane & 15, q = lane >> 4;

    float bb[8][4];
    #pragma unroll
    for (int ct = 0; ct < 8; ++ct)
        #pragma unroll
        for (int r = 0; r < 4; ++r) bb[ct][r] = bias[ct * 16 + q * 4 + r];

    float csum[8][4];
    #pragma unroll
    for (int ct = 0; ct < 8; ++ct)
        #pragma unroll
        for (int r = 0; r < 4; ++r) csum[ct][r] = 0.f;

    #pragma unroll
    for (int grp = 0; grp < 4; ++grp) {
        const int row = blockIdx.x * 256 + grp * 64 + wid * 16 + r15;
        const int rowc = (row < NN) ? row : (NN - 1);
        const bool ok = row < NN;

        f4 acc[8];
        #pragma unroll
        for (int ct = 0; ct < 8; ++ct) acc[ct] = (f4){0.f, 0.f, 0.f, 0.f};

        #pragma unroll
        for (int ks = 0; ks < 8; ++ks) {
            const unsigned short* s = (ks < 4) ? aggb : hinb;
            bf8 bfrag = *(const bf8*)(s + (size_t)rowc * 128 + (ks & 3) * 32 + q * 8);
            #pragma unroll
            for (int ct = 0; ct < 8; ++ct) {
                int j = ct * 16 + r15;
                bf8 wfrag = *(const bf8*)((char*)sW + j * 512 +
                                          ((ks * 64 + q * 16) ^ ((j & 7) << 4)));
                acc[ct] = __builtin_amdgcn_mfma_f32_16x16x32_bf16(wfrag, bfrag, acc[ct], 0, 0, 0);
            }
        }

        #pragma unroll
        for (int ct = 0; ct < 8; ++ct) {
            float o[4];
            #pragma unroll
            for (int r = 0; r < 4; ++r) {
                float v = frelu(acc[ct][r] + bb[ct][r]);
                o[r] = ok ? v : 0.f;
                csum[ct][r] += o[r];
            }
            if (ok && write_h) {
                us4 p;
                p[0] = f2b(o[0]); p[1] = f2b(o[1]); p[2] = f2b(o[2]); p[3] = f2b(o[3]);
                *(us4*)(hout + (size_t)row * 128 + ct * 16 + q * 4) = p;
            }
        }
    }

    // reduce column sums over the 16 rows (lanes r15) per q-group
    #pragma unroll
    for (int ct = 0; ct < 8; ++ct)
        #pragma unroll
        for (int r = 0; r < 4; ++r) {
            float v = csum[ct][r];
            v += __shfl_xor(v, 1);
            v += __shfl_xor(v, 2);
            v += __shfl_xor(v, 4);
            v += __shfl_xor(v, 8);
            csum[ct][r] = v;
        }

    if (r15 == 0) {
        #pragma unroll
        for (int ct = 0; ct < 8; ++ct)
            #pragma unroll
            for (int r = 0; r < 4; ++r)
                red[wid * 128 + ct * 16 + q * 4 + r] = csum[ct][r];
    }
    __syncthreads();
    if (tid < 128) {
        float s = red[tid] + red[128 + tid] + red[256 + tid] + red[384 + tid];
        atomicAdd(&gsum[tid], s);
    }
}

__global__ void k_mlp(const float* __restrict__ gsum,
                      const float* __restrict__ fc1w, const float* __restrict__ fc1b,
                      const float* __restrict__ fc2w, const float* __restrict__ fc2b,
                      const float* __restrict__ fc3w, const float* __restrict__ fc3b,
                      float* __restrict__ out)
{
    __shared__ float g[128], t1[256], t2[128];
    int t = threadIdx.x;
    if (t < 128) g[t] = gsum[t];
    __syncthreads();
    float a = fc1b[t];
    for (int k = 0; k < 128; ++k) a += fc1w[t * 128 + k] * g[k];
    t1[t] = frelu(a);
    __syncthreads();
    if (t < 128) {
        float a2 = fc2b[t];
        for (int k = 0; k < 256; ++k) a2 += fc2w[t * 256 + k] * t1[k];
        t2[t] = frelu(a2);
    }
    __syncthreads();
    if (t < 64) {
        float s = t2[t] * fc3w[t] + t2[t + 64] * fc3w[t + 64];
        for (int o = 32; o; o >>= 1) s += __shfl_down(s, o);
        if (t == 0) out[0] = s + fc3b[0];
    }
}

extern "C" void kernel_launch(void* const* d_in, const int* in_sizes, int n_in,
                              void* d_out, int out_size, void* d_ws, size_t ws_size,
                              hipStream_t stream)
{
    const float* x    = (const float*)d_in[0];
    const int*   ei   = (const int*)d_in[1];
    const float* lwl  = (const float*)d_in[2];
    const float* lbl  = (const float*)d_in[3];
    const float* lwr  = (const float*)d_in[4];
    const float* bnw  = (const float*)d_in[5];
    const float* bnb  = (const float*)d_in[6];
    const float* fc1w = (const float*)d_in[7];
    const float* fc1b = (const float*)d_in[8];
    const float* fc2w = (const float*)d_in[9];
    const float* fc2b = (const float*)d_in[10];
    const float* fc3w = (const float*)d_in[11];
    const float* fc3b = (const float*)d_in[12];
    float* out = (float*)d_out;

    char* ws = (char*)d_ws;
    size_t off = 0;
    auto alloc = [&](size_t b) -> char* {
        char* p = ws + off;
        off = (off + b + 255) & ~(size_t)255;
        return p;
    };
    int*   deg_cnt = (int*)alloc((size_t)NN * 4);
    int*   offs    = (int*)alloc((size_t)(NN + 1) * 4);
    int*   cursor  = (int*)alloc((size_t)NN * 4);
    int*   chunks  = (int*)alloc(64 * 4);
    int*   csr     = (int*)alloc((size_t)NE * 4);
    int*   flag    = (int*)alloc(4);
    float* deginv  = (float*)alloc((size_t)NN * 4);
    unsigned short* w2   = (unsigned short*)alloc((size_t)3 * 128 * 256 * 2);
    float* bias    = (float*)alloc((size_t)3 * 128 * 4);
    float* gsum    = (float*)alloc(128 * 4);
    unsigned short* xbf  = (unsigned short*)alloc((size_t)NN * 128 * 2);
    unsigned short* h    = (unsigned short*)alloc((size_t)NN * 128 * 2);
    unsigned short* agg  = (unsigned short*)alloc((size_t)NN * 128 * 2);

    hipMemsetAsync(deg_cnt, 0, (size_t)NN * 4, stream);
    hipMemsetAsync(gsum, 0, 128 * 4, stream);

    k_detect<<<1, 64, 0, stream>>>(ei, flag);
    k_count<<<(NE + 255) / 256, 256, 0, stream>>>(ei, flag, deg_cnt);
    k_scan1<<<NCHUNK, 256, 0, stream>>>(deg_cnt, offs, chunks);
    k_scan2<<<1, 64, 0, stream>>>(chunks, offs);
    k_add2<<<(NN + 255) / 256, 256, 0, stream>>>(offs, chunks, cursor, deg_cnt, deginv);
    k_fill<<<(NE + 255) / 256, 256, 0, stream>>>(ei, flag, cursor, csr);
    k_fold<<<(3 * 128 * 256) / 256, 256, 0, stream>>>(lwl, lbl, lwr, bnw, bnb, w2, bias);
    k_cvtsum<<<512, 256, 0, stream>>>(x, xbf, gsum);

    const unsigned short* hin = xbf;
    for (int l = 0; l < 3; ++l) {
        k_gather<<<(NN * 64) / 256, 256, 0, stream>>>(hin, offs, csr, deginv, agg);
        k_combine<<<(NN + 255) / 256, 256, 0, stream>>>(
            agg, hin, w2 + (size_t)l * 128 * 256, bias + (size_t)l * 128,
            h, gsum, (l < 2) ? 1 : 0);
        hin = h;
    }
    k_mlp<<<1, 256, 0, stream>>>(gsum, fc1w, fc1b, fc2w, fc2b, fc3w, fc3b, out);
}